// Round 12
// baseline (407.859 us; speedup 1.0000x reference)
//
#include <hip/hip_runtime.h>
#include <stdint.h>

#define NB    32
#define NN    2048
#define NR    100
#define TOPK  256      // rows/cols precomputed; walk ends ~row 104 (validated r5-r8)
#define MCAND 320      // candidate cap for the fast top-K path
#define NBIN  4096

// ---------------------------------------------------------------------------
// One block per batch, everything in LDS, zero inter-block communication.
//  1. keys[i] = (~ordered(score_i) << 32) | i   (ascending key = exact
//     jnp.argsort(-scores) order, stable tie-break by index).
//  2. 4096-bin histogram on akey[31:20]; B* = smallest bin with cum >= 256.
//  3. candidates = keys in bins <= B*  (superset of the top-256; m>=256).
//  4. exact stable rank among m candidates (m^2 compares, m~258); scatter
//     top-256 boxes + thresholds 0.5f*area into LDS.
//     Exact ref semantics: RN(inter/aj) >= 0.5 <=> inter >= 0.5f*aj (the true
//     threshold c - c*2^-25 lies in (pred(c), c); no f32 exists there).
//  5. 256x256-bit suppression matrix M in LDS (8 KB), upper triangle,
//     20 wave-tiles of 64 rows x 32 cols.
//  6. serial greedy walk (wave 0) over LDS M; early exit at 100 kept.
//  Fallback (m > MCAND, or <100 kept by row 256 — degenerate inputs only):
//  exact full 2048-rank + on-the-fly walk, still entirely in-block.
// ---------------------------------------------------------------------------
__global__ __launch_bounds__(1024) void nms_all(const float* __restrict__ pred,
                                                float* __restrict__ out) {
    __shared__ uint64_t keys[NN];                 // 16 KB, live for whole kernel
    __shared__ union {
        struct {
            uint32_t hist[NBIN];                  // 16 KB
            uint64_t cand[MCAND];                 // 2.5 KB
            float4   cbox[TOPK];                  // 4 KB  (l,t,r,b)
            float    cthr[TOPK];                  // 1 KB  (0.5f*area)
            uint32_t M[TOPK][8];                  // 8 KB
        } f;
        struct { float4 box[NN]; } fb;            // 32 KB (fallback full sort)
    } u;
    __shared__ int wsum[16];
    __shared__ int woff[16];
    __shared__ int slots[NR];
    __shared__ int s_cnt, s_bstar, s_count, s_fall;

    const int b    = blockIdx.x;
    const int tid  = threadIdx.x;
    const int wv   = tid >> 6;
    const int lane = tid & 63;
    const float* p = pred + (size_t)b * NN * 5;

    // ---- 1. keys + init ----
    if (tid == 0) { s_cnt = 0; s_fall = 0; }
    for (int i = tid; i < NBIN; i += 1024) u.f.hist[i] = 0;
    for (int i = tid; i < NN; i += 1024) {
        uint32_t uu  = __float_as_uint(p[i * 5]);
        uint32_t ord = (uu & 0x80000000u) ? ~uu : (uu | 0x80000000u);
        keys[i] = ((uint64_t)(~ord) << 32) | (uint32_t)i;
    }
    __syncthreads();

    // ---- 2. histogram + find B* ----
    for (int i = tid; i < NN; i += 1024)
        atomicAdd(&u.f.hist[(uint32_t)(keys[i] >> 52)], 1u);
    __syncthreads();
    {
        int h[4], psum = 0;
#pragma unroll
        for (int q = 0; q < 4; ++q) { h[q] = (int)u.f.hist[tid * 4 + q]; psum += h[q]; }
        int sc = psum;                       // wave-inclusive scan
#pragma unroll
        for (int d = 1; d < 64; d <<= 1) {
            int n = __shfl_up(sc, d);
            if (lane >= d) sc += n;
        }
        if (lane == 63) wsum[wv] = sc;
        __syncthreads();
        if (tid == 0) {
            int off = 0;
            for (int w = 0; w < 16; ++w) { woff[w] = off; off += wsum[w]; }
        }
        __syncthreads();
        int cum = woff[wv] + (sc - psum);    // exclusive prefix before my 4 bins
#pragma unroll
        for (int q = 0; q < 4; ++q) {
            if (cum < TOPK && cum + h[q] >= TOPK) s_bstar = tid * 4 + q;
            cum += h[q];
        }
    }
    __syncthreads();
    const uint32_t bstar = (uint32_t)s_bstar;

    // ---- 3. collect candidates ----
    for (int i = tid; i < NN; i += 1024) {
        if ((uint32_t)(keys[i] >> 52) <= bstar) {
            int pos = atomicAdd(&s_cnt, 1);
            if (pos < MCAND) u.f.cand[pos] = keys[i];
        }
    }
    __syncthreads();
    const int m = s_cnt;
    if (tid == 0 && m > MCAND) s_fall = 1;
    __syncthreads();

    if (!s_fall) {
        // ---- 4. exact rank among candidates, scatter top-256 ----
        if (tid < m) {
            uint64_t k = u.f.cand[tid];
            int r = 0;
            for (int j = 0; j < m; ++j)       // wave-uniform LDS broadcast
                r += (u.f.cand[j] < k);
            if (r < TOPK) {
                int idx = (int)(uint32_t)k;
                const float* q = p + (size_t)idx * 5;
                float l = q[1], t = q[2], rr = q[3], bb = q[4];
                u.f.cbox[r] = make_float4(l, t, rr, bb);
                u.f.cthr[r] = 0.5f * ((rr - l) * (bb - t));
            }
        }
        for (int i = tid; i < TOPK * 8; i += 1024)
            ((uint32_t*)u.f.M)[i] = 0;
        __syncthreads();

        // ---- 5. pairs: 20 upper-tri wave-tiles (64 rows x 32 cols) ----
        for (int t = wv; t < 20; t += 16) {
            int rt, ct;
            if      (t < 8)  { rt = 0; ct = t;      }
            else if (t < 14) { rt = 1; ct = t - 6;  }
            else if (t < 18) { rt = 2; ct = t - 10; }
            else             { rt = 3; ct = t - 12; }
            const int i = rt * 64 + lane;
            const float4 bi = u.f.cbox[i];
            const int jb = ct * 32;
            uint32_t roww = 0;
#pragma unroll
            for (int k = 0; k < 32; ++k) {
                float4 cb = u.f.cbox[jb + k];   // wave-uniform broadcast
                float  cc = u.f.cthr[jb + k];
                float il = fmaxf(bi.x, cb.x);
                float iy = fmaxf(bi.y, cb.y);
                float ir = fminf(bi.z, cb.z);
                float ib = fminf(bi.w, cb.w);
                float inter = fmaxf(ir - il, 0.0f) * fmaxf(ib - iy, 0.0f);
                roww |= (inter >= cc) ? (1u << k) : 0u;  // bit k = col jb+k
            }
            const int d = i - jb;                // mask cols j <= i
            uint32_t um = (d < 0) ? 0xFFFFFFFFu
                                  : ((d >= 31) ? 0u : (0xFFFFFFFFu << (d + 1)));
            u.f.M[i][ct] = roww & um;
        }
        __syncthreads();

        // ---- 6. walk (wave 0), all in LDS ----
        if (wv == 0) {
            uint32_t keep = 0xFFFFFFFFu;         // lane L<8 owns rows 32L..32L+31
            int count = 0;
            for (int i = 0; i < TOPK; ++i) {
                uint32_t kw = __shfl(keep, i >> 5);      // wave-uniform
                if ((kw >> (i & 31)) & 1u) {
                    uint32_t mw = (lane < 8) ? u.f.M[i][lane] : 0u;
                    keep &= ~mw;
                    if (lane == 0 && count < NR) slots[count] = i;
                    ++count;
                    if (count >= NR) break;      // first 100 kept are final
                }
            }
            if (lane == 0) s_count = count;
        }
        __syncthreads();
        if (tid == 0 && s_count < NR) s_fall = 1;   // degenerate: need rows >= 256
        __syncthreads();

        if (!s_fall) {
            const int count = s_count;
            for (int s = tid; s < NR; s += 1024) {
                float x = 0.f, y = 0.f, z = 0.f;
                if (s < count) {
                    float4 q4 = u.f.cbox[slots[s]];
                    x = q4.y; y = q4.z; z = q4.w;  // vals = (top, right, bottom)
                }
                float* o = out + ((size_t)b * NR + s) * 3;
                o[0] = x; o[1] = y; o[2] = z;
            }
            return;                               // fast path done
        }
    }

    // ---------------- exact fallback (degenerate inputs only) ----------------
    __syncthreads();
    {   // full 2048 rank-by-counting into LDS boxes
        uint64_t k0 = keys[tid], k1 = keys[tid + 1024];
        int r0 = 0, r1 = 0;
        const ulonglong2* k2 = (const ulonglong2*)keys;
        for (int j = 0; j < NN / 2; ++j) {
            ulonglong2 kk = k2[j];
            r0 += (kk.x < k0) + (kk.y < k0);
            r1 += (kk.x < k1) + (kk.y < k1);
        }
        const float* q0 = p + (size_t)tid * 5;
        const float* q1 = p + (size_t)(tid + 1024) * 5;
        u.fb.box[r0] = make_float4(q0[1], q0[2], q0[3], q0[4]);
        u.fb.box[r1] = make_float4(q1[1], q1[2], q1[3], q1[4]);
    }
    __syncthreads();
    if (wv == 0) {
        uint32_t keep = 0xFFFFFFFFu;             // lane L owns rows 32L..32L+31
        int count = 0;
        for (int i = 0; i < NN; ++i) {
            uint32_t kw = __shfl(keep, i >> 5);
            if ((kw >> (i & 31)) & 1u) {
                float4 bi = u.fb.box[i];
                uint32_t kill = 0;
                for (int t = 0; t < 32; ++t) {
                    int j = lane * 32 + t;
                    if (j > i) {
                        float4 bj = u.fb.box[j];
                        float cc = 0.5f * ((bj.z - bj.x) * (bj.w - bj.y));
                        float il = fmaxf(bi.x, bj.x);
                        float iy = fmaxf(bi.y, bj.y);
                        float ir = fminf(bi.z, bj.z);
                        float ib = fminf(bi.w, bj.w);
                        float inter = fmaxf(ir - il, 0.0f) * fmaxf(ib - iy, 0.0f);
                        if (inter >= cc) kill |= (1u << t);
                    }
                }
                keep &= ~kill;
                if (lane == 0 && count < NR) slots[count] = i;
                ++count;
                if (count >= NR) break;
            }
        }
        if (lane == 0) s_count = count;
    }
    __syncthreads();
    {
        const int count = s_count;
        for (int s = tid; s < NR; s += 1024) {
            float x = 0.f, y = 0.f, z = 0.f;
            if (s < count) {
                float4 q4 = u.fb.box[slots[s]];
                x = q4.y; y = q4.z; z = q4.w;
            }
            float* o = out + ((size_t)b * NR + s) * 3;
            o[0] = x; o[1] = y; o[2] = z;
        }
    }
}

// ---------------------------------------------------------------------------
extern "C" void kernel_launch(void* const* d_in, const int* in_sizes, int n_in,
                              void* d_out, int out_size, void* d_ws, size_t ws_size,
                              hipStream_t stream) {
    const float* pred = (const float*)d_in[0];
    float* out = (float*)d_out;
    nms_all<<<NB, 1024, 0, stream>>>(pred, out);
}

// Round 13
// 38.894 us; speedup vs baseline: 10.4865x; 10.4865x over previous
//
#include <hip/hip_runtime.h>
#include <stdint.h>

#define NB    32
#define NN    2048
#define NR    100
#define TOPK  256      // rows/cols precomputed; walk ends ~row 104 (validated r5-r8)
#define MCAND 512      // candidate cap; uniform-score bins ~128 keys -> m in [256,384)
#define NBIN  4096

// ---------------------------------------------------------------------------
// One block per batch, everything in LDS, zero inter-block communication.
//  1. keys[i] = (~ordered(score_i) << 32) | i   (ascending key = exact
//     jnp.argsort(-scores) order, stable tie-break by index).
//  2. 4096-bin histogram on key[63:52]; B* = smallest bin with cum >= 256.
//  3. candidates = keys in bins <= B*  (superset of the top-256; m >= 256).
//  4. exact stable rank among m candidates (m^2 compares, m~300); scatter
//     top-256 boxes + thresholds 0.5f*area into LDS.
//     Exact ref semantics: RN(inter/aj) >= 0.5 <=> inter >= 0.5f*aj (the true
//     threshold c - c*2^-25 lies in (pred(c), c); no f32 exists there).
//  5. 256x256-bit suppression matrix M in LDS (8 KB), upper triangle,
//     20 wave-tiles of 64 rows x 32 cols.
//  6. serial greedy walk (wave 0) over LDS M; early exit at 100 kept.
//  Fallback (m > MCAND, or <100 kept by row 256 — degenerate inputs only):
//  exact full 2048-rank + on-the-fly walk with interleaved col ownership
//  (coalesced box reads, no 64-way LDS conflicts), still entirely in-block.
// ---------------------------------------------------------------------------
__global__ __launch_bounds__(1024) void nms_all(const float* __restrict__ pred,
                                                float* __restrict__ out) {
    __shared__ uint64_t keys[NN];                 // 16 KB, live for whole kernel
    __shared__ union {
        struct {
            uint32_t hist[NBIN];                  // 16 KB
            uint64_t cand[MCAND];                 // 4 KB
            float4   cbox[TOPK];                  // 4 KB  (l,t,r,b)
            float    cthr[TOPK];                  // 1 KB  (0.5f*area)
            uint32_t M[TOPK][8];                  // 8 KB
        } f;
        struct { float4 box[NN]; } fb;            // 32 KB (fallback full sort)
    } u;
    __shared__ int wsum[16];
    __shared__ int woff[16];
    __shared__ int slots[NR];
    __shared__ int s_cnt, s_bstar, s_count, s_fall;

    const int b    = blockIdx.x;
    const int tid  = threadIdx.x;
    const int wv   = tid >> 6;
    const int lane = tid & 63;
    const float* p = pred + (size_t)b * NN * 5;

    // ---- 1. keys + init ----
    if (tid == 0) { s_cnt = 0; s_fall = 0; }
    for (int i = tid; i < NBIN; i += 1024) u.f.hist[i] = 0;
    for (int i = tid; i < NN; i += 1024) {
        uint32_t uu  = __float_as_uint(p[i * 5]);
        uint32_t ord = (uu & 0x80000000u) ? ~uu : (uu | 0x80000000u);
        keys[i] = ((uint64_t)(~ord) << 32) | (uint32_t)i;
    }
    __syncthreads();

    // ---- 2. histogram + find B* ----
    for (int i = tid; i < NN; i += 1024)
        atomicAdd(&u.f.hist[(uint32_t)(keys[i] >> 52)], 1u);
    __syncthreads();
    {
        int h[4], psum = 0;
#pragma unroll
        for (int q = 0; q < 4; ++q) { h[q] = (int)u.f.hist[tid * 4 + q]; psum += h[q]; }
        int sc = psum;                       // wave-inclusive scan
#pragma unroll
        for (int d = 1; d < 64; d <<= 1) {
            int n = __shfl_up(sc, d);
            if (lane >= d) sc += n;
        }
        if (lane == 63) wsum[wv] = sc;
        __syncthreads();
        if (tid == 0) {
            int off = 0;
            for (int w = 0; w < 16; ++w) { woff[w] = off; off += wsum[w]; }
        }
        __syncthreads();
        int cum = woff[wv] + (sc - psum);    // exclusive prefix before my 4 bins
#pragma unroll
        for (int q = 0; q < 4; ++q) {
            if (cum < TOPK && cum + h[q] >= TOPK) s_bstar = tid * 4 + q;
            cum += h[q];
        }
    }
    __syncthreads();
    const uint32_t bstar = (uint32_t)s_bstar;

    // ---- 3. collect candidates ----
    for (int i = tid; i < NN; i += 1024) {
        if ((uint32_t)(keys[i] >> 52) <= bstar) {
            int pos = atomicAdd(&s_cnt, 1);
            if (pos < MCAND) u.f.cand[pos] = keys[i];
        }
    }
    __syncthreads();
    const int m = s_cnt;
    if (tid == 0 && m > MCAND) s_fall = 1;
    __syncthreads();

    if (!s_fall) {
        // ---- 4. exact rank among candidates, scatter top-256 ----
        if (tid < m) {
            uint64_t k = u.f.cand[tid];
            int r = 0;
            for (int j = 0; j < m; ++j)       // wave-uniform LDS broadcast
                r += (u.f.cand[j] < k);
            if (r < TOPK) {
                int idx = (int)(uint32_t)k;
                const float* q = p + (size_t)idx * 5;
                float l = q[1], t = q[2], rr = q[3], bb = q[4];
                u.f.cbox[r] = make_float4(l, t, rr, bb);
                u.f.cthr[r] = 0.5f * ((rr - l) * (bb - t));
            }
        }
        for (int i = tid; i < TOPK * 8; i += 1024)
            ((uint32_t*)u.f.M)[i] = 0;
        __syncthreads();

        // ---- 5. pairs: 20 upper-tri wave-tiles (64 rows x 32 cols) ----
        for (int t = wv; t < 20; t += 16) {
            int rt, ct;
            if      (t < 8)  { rt = 0; ct = t;      }
            else if (t < 14) { rt = 1; ct = t - 6;  }
            else if (t < 18) { rt = 2; ct = t - 10; }
            else             { rt = 3; ct = t - 12; }
            const int i = rt * 64 + lane;
            const float4 bi = u.f.cbox[i];
            const int jb = ct * 32;
            uint32_t roww = 0;
#pragma unroll
            for (int k = 0; k < 32; ++k) {
                float4 cb = u.f.cbox[jb + k];   // wave-uniform broadcast
                float  cc = u.f.cthr[jb + k];
                float il = fmaxf(bi.x, cb.x);
                float iy = fmaxf(bi.y, cb.y);
                float ir = fminf(bi.z, cb.z);
                float ib = fminf(bi.w, cb.w);
                float inter = fmaxf(ir - il, 0.0f) * fmaxf(ib - iy, 0.0f);
                roww |= (inter >= cc) ? (1u << k) : 0u;  // bit k = col jb+k
            }
            const int d = i - jb;                // mask cols j <= i
            uint32_t um = (d < 0) ? 0xFFFFFFFFu
                                  : ((d >= 31) ? 0u : (0xFFFFFFFFu << (d + 1)));
            u.f.M[i][ct] = roww & um;
        }
        __syncthreads();

        // ---- 6. walk (wave 0), all in LDS ----
        if (wv == 0) {
            uint32_t keep = 0xFFFFFFFFu;         // lane L<8 owns cols 32L..32L+31
            int count = 0;
            for (int i = 0; i < TOPK; ++i) {
                uint32_t kw = __shfl(keep, i >> 5);      // wave-uniform
                if ((kw >> (i & 31)) & 1u) {
                    uint32_t mw = (lane < 8) ? u.f.M[i][lane] : 0u;
                    keep &= ~mw;
                    if (lane == 0 && count < NR) slots[count] = i;
                    ++count;
                    if (count >= NR) break;      // first 100 kept are final
                }
            }
            if (lane == 0) s_count = count;
        }
        __syncthreads();
        if (tid == 0 && s_count < NR) s_fall = 1;   // degenerate: need rows >= 256
        __syncthreads();

        if (!s_fall) {
            const int count = s_count;
            for (int s = tid; s < NR; s += 1024) {
                float x = 0.f, y = 0.f, z = 0.f;
                if (s < count) {
                    float4 q4 = u.f.cbox[slots[s]];
                    x = q4.y; y = q4.z; z = q4.w;  // vals = (top, right, bottom)
                }
                float* o = out + ((size_t)b * NR + s) * 3;
                o[0] = x; o[1] = y; o[2] = z;
            }
            return;                               // fast path done
        }
    }

    // ---------------- exact fallback (degenerate inputs only) ----------------
    __syncthreads();
    {   // full 2048 rank-by-counting into LDS boxes
        uint64_t k0 = keys[tid], k1 = keys[tid + 1024];
        int r0 = 0, r1 = 0;
        const ulonglong2* k2 = (const ulonglong2*)keys;
        for (int j = 0; j < NN / 2; ++j) {
            ulonglong2 kk = k2[j];
            r0 += (kk.x < k0) + (kk.y < k0);
            r1 += (kk.x < k1) + (kk.y < k1);
        }
        const float* q0 = p + (size_t)tid * 5;
        const float* q1 = p + (size_t)(tid + 1024) * 5;
        u.fb.box[r0] = make_float4(q0[1], q0[2], q0[3], q0[4]);
        u.fb.box[r1] = make_float4(q1[1], q1[2], q1[3], q1[4]);
    }
    __syncthreads();
    if (wv == 0) {
        // Interleaved ownership: lane L owns cols j with (j&63)==L, bit t=j>>6.
        // Box reads box[t*64+lane] are consecutive float4 -> no 64-way conflict.
        uint32_t keep = 0xFFFFFFFFu;
        int count = 0;
        for (int i = 0; i < NN; ++i) {
            uint32_t kw = __shfl(keep, i & 63);
            if ((kw >> (i >> 6)) & 1u) {
                float4 bi = u.fb.box[i];             // wave-uniform broadcast
                uint32_t kill = 0;
#pragma unroll 4
                for (int t = 0; t < 32; ++t) {
                    int j = t * 64 + lane;
                    if (j > i) {
                        float4 bj = u.fb.box[j];     // coalesced across lanes
                        float cc = 0.5f * ((bj.z - bj.x) * (bj.w - bj.y));
                        float il = fmaxf(bi.x, bj.x);
                        float iy = fmaxf(bi.y, bj.y);
                        float ir = fminf(bi.z, bj.z);
                        float ib = fminf(bi.w, bj.w);
                        float inter = fmaxf(ir - il, 0.0f) * fmaxf(ib - iy, 0.0f);
                        if (inter >= cc) kill |= (1u << t);
                    }
                }
                keep &= ~kill;
                if (lane == 0 && count < NR) slots[count] = i;
                ++count;
                if (count >= NR) break;
            }
        }
        if (lane == 0) s_count = count;
    }
    __syncthreads();
    {
        const int count = s_count;
        for (int s = tid; s < NR; s += 1024) {
            float x = 0.f, y = 0.f, z = 0.f;
            if (s < count) {
                float4 q4 = u.fb.box[slots[s]];
                x = q4.y; y = q4.z; z = q4.w;
            }
            float* o = out + ((size_t)b * NR + s) * 3;
            o[0] = x; o[1] = y; o[2] = z;
        }
    }
}

// ---------------------------------------------------------------------------
extern "C" void kernel_launch(void* const* d_in, const int* in_sizes, int n_in,
                              void* d_out, int out_size, void* d_ws, size_t ws_size,
                              hipStream_t stream) {
    const float* pred = (const float*)d_in[0];
    float* out = (float*)d_out;
    nms_all<<<NB, 1024, 0, stream>>>(pred, out);
}

// Round 14
// 28.557 us; speedup vs baseline: 14.2825x; 1.3620x over previous
//
#include <hip/hip_runtime.h>
#include <stdint.h>

#define NB    32
#define NN    2048
#define NR    100
#define TOPK  256      // rows/cols precomputed; walk ends ~row 104 (validated r5-r8)
#define MCAND 512      // candidate cap; uniform-score bins ~170 keys -> m in [256,430)
#define NBIN  4096

// ---------------------------------------------------------------------------
// One block per batch, everything in LDS, zero inter-block communication.
//  1. keys[i] = (~ordered(score_i) << 32) | i  (ascending = argsort(-scores)).
//  2. 4096-bin histogram on key[63:52]; B* = first bin with cum >= 256.
//  3. candidates = keys in bins <= B* (superset of top-256); boxes gathered
//     into LDS during collection (16-wave phase, HBM latency overlapped).
//  4. exact stable rank among m candidates — FIXED-TRIP unrolled loop over
//     0xFF..FF-padded cand[] in groups of 8 (2x b128 reads, batched waits);
//     scatter top-256 boxes + thresholds 0.5f*area.
//     Exact ref semantics: RN(inter/aj) >= 0.5 <=> inter >= 0.5f*aj (the true
//     threshold c - c*2^-25 lies in (pred(c), c); no f32 exists there).
//  5. 256x256-bit suppression matrix M in LDS, upper triangle, 20 wave-tiles.
//  6. walk (wave 0) with keep REPLICATED in all lanes (8 u32, statically
//     indexed via unrolled word loop): alive-check = uniform VALU (no shfl);
//     M rows prefetched 4-deep via uniform broadcast uint4 reads.
//  Fallback (m > MCAND or <100 kept by row 256 — degenerate only): exact
//  full 2048-rank + on-the-fly walk, interleaved col ownership, in-block.
// ---------------------------------------------------------------------------
__global__ __launch_bounds__(1024) void nms_all(const float* __restrict__ pred,
                                                float* __restrict__ out) {
    __shared__ uint64_t keys[NN];                 // 16 KB, live whole kernel
    __shared__ union {
        struct {
            uint32_t hist[NBIN];                  // 16 KB
            alignas(16) uint64_t cand[MCAND];     // 4 KB
            float4   ctmp[MCAND];                 // 8 KB (gathered boxes, unsorted)
            float4   cbox[TOPK];                  // 4 KB (l,t,r,b) sorted
            float    cthr[TOPK];                  // 1 KB (0.5f*area)
            alignas(16) uint32_t M[TOPK][8];      // 8 KB
        } f;
        struct { float4 box[NN]; } fb;            // 32 KB (fallback full sort)
    } u;
    __shared__ int wsum[16];
    __shared__ int woff[16];
    __shared__ int slots[NR];
    __shared__ int s_cnt, s_bstar, s_count, s_fall;

    const int b    = blockIdx.x;
    const int tid  = threadIdx.x;
    const int wv   = tid >> 6;
    const int lane = tid & 63;
    const float* p = pred + (size_t)b * NN * 5;

    // ---- 1. keys + init ----
    if (tid == 0) { s_cnt = 0; s_fall = 0; }
    for (int i = tid; i < NBIN; i += 1024) u.f.hist[i] = 0;
    for (int i = tid; i < MCAND; i += 1024) u.f.cand[i] = ~0ull;  // pad sentinel
    for (int i = tid; i < NN; i += 1024) {
        uint32_t uu  = __float_as_uint(p[i * 5]);
        uint32_t ord = (uu & 0x80000000u) ? ~uu : (uu | 0x80000000u);
        keys[i] = ((uint64_t)(~ord) << 32) | (uint32_t)i;
    }
    __syncthreads();

    // ---- 2. histogram + find B* ----
    for (int i = tid; i < NN; i += 1024)
        atomicAdd(&u.f.hist[(uint32_t)(keys[i] >> 52)], 1u);
    __syncthreads();
    {
        int h[4], psum = 0;
#pragma unroll
        for (int q = 0; q < 4; ++q) { h[q] = (int)u.f.hist[tid * 4 + q]; psum += h[q]; }
        int sc = psum;                       // wave-inclusive scan
#pragma unroll
        for (int d = 1; d < 64; d <<= 1) {
            int n = __shfl_up(sc, d);
            if (lane >= d) sc += n;
        }
        if (lane == 63) wsum[wv] = sc;
        __syncthreads();
        if (wv == 0 && lane < 16) {          // parallel 16-entry scan
            int v = wsum[lane], s2 = v;
#pragma unroll
            for (int d = 1; d < 16; d <<= 1) {
                int n = __shfl_up(s2, d);
                if (lane >= d) s2 += n;
            }
            woff[lane] = s2 - v;
        }
        __syncthreads();
        int cum = woff[wv] + (sc - psum);    // exclusive prefix before my 4 bins
#pragma unroll
        for (int q = 0; q < 4; ++q) {
            if (cum < TOPK && cum + h[q] >= TOPK) s_bstar = tid * 4 + q;
            cum += h[q];
        }
    }
    __syncthreads();
    const uint32_t bstar = (uint32_t)s_bstar;

    // ---- 3. collect candidates + gather their boxes (16-wave phase) ----
    for (int i = tid; i < NN; i += 1024) {
        if ((uint32_t)(keys[i] >> 52) <= bstar) {
            int pos = atomicAdd(&s_cnt, 1);
            if (pos < MCAND) {
                u.f.cand[pos] = keys[i];
                const float* q = p + (size_t)i * 5;
                u.f.ctmp[pos] = make_float4(q[1], q[2], q[3], q[4]);
            }
        }
    }
    __syncthreads();
    const int m = s_cnt;
    if (tid == 0 && m > MCAND) s_fall = 1;
    __syncthreads();

    if (!s_fall) {
        // ---- 4. exact rank among candidates (fixed-step unrolled) ----
        if (tid < m) {
            const uint64_t k = u.f.cand[tid];
            const int mp = (m + 7) & ~7;
            int r = 0;
            for (int j = 0; j < mp; j += 8) {        // 2x b128 per group
                const ulonglong2* c2 = (const ulonglong2*)(u.f.cand + j);
                ulonglong2 a0 = c2[0], a1 = c2[1], a2 = c2[2], a3 = c2[3];
                r += (int)(a0.x < k) + (int)(a0.y < k)
                   + (int)(a1.x < k) + (int)(a1.y < k)
                   + (int)(a2.x < k) + (int)(a2.y < k)
                   + (int)(a3.x < k) + (int)(a3.y < k);
            }
            if (r < TOPK) {
                float4 v = u.f.ctmp[tid];
                u.f.cbox[r] = v;
                u.f.cthr[r] = 0.5f * ((v.z - v.x) * (v.w - v.y));
            }
        }
        for (int i = tid; i < TOPK * 8; i += 1024)
            ((uint32_t*)u.f.M)[i] = 0;
        __syncthreads();

        // ---- 5. pairs: 20 upper-tri wave-tiles (64 rows x 32 cols) ----
        for (int t = wv; t < 20; t += 16) {
            int rt, ct;
            if      (t < 8)  { rt = 0; ct = t;      }
            else if (t < 14) { rt = 1; ct = t - 6;  }
            else if (t < 18) { rt = 2; ct = t - 10; }
            else             { rt = 3; ct = t - 12; }
            const int i = rt * 64 + lane;
            const float4 bi = u.f.cbox[i];
            const int jb = ct * 32;
            uint32_t roww = 0;
#pragma unroll
            for (int k = 0; k < 32; ++k) {
                float4 cb = u.f.cbox[jb + k];   // wave-uniform broadcast
                float  cc = u.f.cthr[jb + k];
                float il = fmaxf(bi.x, cb.x);
                float iy = fmaxf(bi.y, cb.y);
                float ir = fminf(bi.z, cb.z);
                float ib = fminf(bi.w, cb.w);
                float inter = fmaxf(ir - il, 0.0f) * fmaxf(ib - iy, 0.0f);
                roww |= (inter >= cc) ? (1u << k) : 0u;  // bit k = col jb+k
            }
            const int d = i - jb;                // mask cols j <= i
            uint32_t um = (d < 0) ? 0xFFFFFFFFu
                                  : ((d >= 31) ? 0u : (0xFFFFFFFFu << (d + 1)));
            u.f.M[i][ct] = roww & um;
        }
        __syncthreads();

        // ---- 6. walk (wave 0): replicated keep, no shfl, 4-row prefetch ----
        if (wv == 0) {
            uint32_t kp[8];
#pragma unroll
            for (int w = 0; w < 8; ++w) kp[w] = 0xFFFFFFFFu;
            int count = 0;
#pragma unroll
            for (int w = 0; w < 8; ++w) {        // static word index (rule #20)
                for (int i0 = w * 32; i0 < w * 32 + 32; i0 += 4) {
                    uint4 ra[4], rb[4];
#pragma unroll
                    for (int g = 0; g < 4; ++g) { // uniform broadcast reads
                        ra[g] = *(const uint4*)&u.f.M[i0 + g][0];
                        rb[g] = *(const uint4*)&u.f.M[i0 + g][4];
                    }
#pragma unroll
                    for (int g = 0; g < 4; ++g) {
                        const int i = i0 + g;
                        if ((kp[w] >> (i & 31)) & 1u) {   // uniform VALU check
                            kp[0] &= ~ra[g].x; kp[1] &= ~ra[g].y;
                            kp[2] &= ~ra[g].z; kp[3] &= ~ra[g].w;
                            kp[4] &= ~rb[g].x; kp[5] &= ~rb[g].y;
                            kp[6] &= ~rb[g].z; kp[7] &= ~rb[g].w;
                            if (lane == 0 && count < NR) slots[count] = i;
                            ++count;
                        }
                    }
                    if (count >= NR) break;      // first 100 kept are final
                }
                if (count >= NR) break;
            }
            if (lane == 0) s_count = count;
        }
        __syncthreads();
        if (tid == 0 && s_count < NR) s_fall = 1;   // degenerate: need rows >= 256
        __syncthreads();

        if (!s_fall) {
            const int count = s_count;
            for (int s = tid; s < NR; s += 1024) {
                float x = 0.f, y = 0.f, z = 0.f;
                if (s < count) {
                    float4 q4 = u.f.cbox[slots[s]];
                    x = q4.y; y = q4.z; z = q4.w;  // vals = (top, right, bottom)
                }
                float* o = out + ((size_t)b * NR + s) * 3;
                o[0] = x; o[1] = y; o[2] = z;
            }
            return;                               // fast path done
        }
    }

    // ---------------- exact fallback (degenerate inputs only) ----------------
    __syncthreads();
    {   // full 2048 rank-by-counting into LDS boxes
        uint64_t k0 = keys[tid], k1 = keys[tid + 1024];
        int r0 = 0, r1 = 0;
        const ulonglong2* k2 = (const ulonglong2*)keys;
        for (int j = 0; j < NN / 2; ++j) {
            ulonglong2 kk = k2[j];
            r0 += (kk.x < k0) + (kk.y < k0);
            r1 += (kk.x < k1) + (kk.y < k1);
        }
        const float* q0 = p + (size_t)tid * 5;
        const float* q1 = p + (size_t)(tid + 1024) * 5;
        u.fb.box[r0] = make_float4(q0[1], q0[2], q0[3], q0[4]);
        u.fb.box[r1] = make_float4(q1[1], q1[2], q1[3], q1[4]);
    }
    __syncthreads();
    if (wv == 0) {
        // Interleaved ownership: lane L owns cols j with (j&63)==L, bit t=j>>6.
        uint32_t keep = 0xFFFFFFFFu;
        int count = 0;
        for (int i = 0; i < NN; ++i) {
            uint32_t kw = __shfl(keep, i & 63);
            if ((kw >> (i >> 6)) & 1u) {
                float4 bi = u.fb.box[i];             // wave-uniform broadcast
                uint32_t kill = 0;
#pragma unroll 4
                for (int t = 0; t < 32; ++t) {
                    int j = t * 64 + lane;
                    if (j > i) {
                        float4 bj = u.fb.box[j];     // coalesced across lanes
                        float cc = 0.5f * ((bj.z - bj.x) * (bj.w - bj.y));
                        float il = fmaxf(bi.x, bj.x);
                        float iy = fmaxf(bi.y, bj.y);
                        float ir = fminf(bi.z, bj.z);
                        float ib = fminf(bi.w, bj.w);
                        float inter = fmaxf(ir - il, 0.0f) * fmaxf(ib - iy, 0.0f);
                        if (inter >= cc) kill |= (1u << t);
                    }
                }
                keep &= ~kill;
                if (lane == 0 && count < NR) slots[count] = i;
                ++count;
                if (count >= NR) break;
            }
        }
        if (lane == 0) s_count = count;
    }
    __syncthreads();
    {
        const int count = s_count;
        for (int s = tid; s < NR; s += 1024) {
            float x = 0.f, y = 0.f, z = 0.f;
            if (s < count) {
                float4 q4 = u.fb.box[slots[s]];
                x = q4.y; y = q4.z; z = q4.w;
            }
            float* o = out + ((size_t)b * NR + s) * 3;
            o[0] = x; o[1] = y; o[2] = z;
        }
    }
}

// ---------------------------------------------------------------------------
extern "C" void kernel_launch(void* const* d_in, const int* in_sizes, int n_in,
                              void* d_out, int out_size, void* d_ws, size_t ws_size,
                              hipStream_t stream) {
    const float* pred = (const float*)d_in[0];
    float* out = (float*)d_out;
    nms_all<<<NB, 1024, 0, stream>>>(pred, out);
}